// Round 4
// baseline (120.790 us; speedup 1.0000x reference)
//
#include <hip/hip_runtime.h>
#include <math.h>

#define DET 512
#define NA  180
#define OUT 362   // floor(sqrt(512^2/2))
#define RAD 181   // OUT/2

#define NSPLIT 3        // angle partitions per (b, tile)
#define APB    60       // angles per block (NA / NSPLIT)
#define CHUNK  5        // angle lines staged per barrier (pair format)
#define PSTRIDE 514     // float2 stride per staged line

constexpr double PI_D = 3.14159265358979323846;

// ---------------------------------------------------------------------------
// Compile-time trig table (indices into it are always block/loop-uniform ->
// compiler emits s_load; NEVER index this with thread-derived values).
// ---------------------------------------------------------------------------
constexpr double tsin(double x) {
    double x2 = x * x;
    return x * (1.0 + x2 * (-1.0/6 + x2 * (1.0/120 + x2 * (-1.0/5040 +
               x2 * (1.0/362880 + x2 * (-1.0/39916800))))));
}
constexpr double tcos(double x) {
    double x2 = x * x;
    return 1.0 + x2 * (-0.5 + x2 * (1.0/24 + x2 * (-1.0/720 +
               x2 * (1.0/40320 + x2 * (-1.0/3628800)))));
}

struct alignas(16) Trig { float c[NA]; float s[NA]; };
constexpr Trig make_trig() {
    Trig t{};
    constexpr double r = PI_D / 180.0;
    for (int k = 0; k < NA; ++k) {
        double c, s;
        if (k <= 45)       { c =  tcos(k * r);          s =  tsin(k * r); }
        else if (k <= 90)  { c =  tsin((90 - k) * r);   s =  tcos((90 - k) * r); }
        else if (k <= 135) { c = -tsin((k - 90) * r);   s =  tcos((k - 90) * r); }
        else               { c = -tcos((180 - k) * r);  s =  tsin((180 - k) * r); }
        t.c[k] = (float)c; t.s[k] = (float)s;
    }
    return t;
}
__device__ constexpr Trig TRIG = make_trig();

// ---------------------------------------------------------------------------
// Ramp-filter weight table for the parity-blocked conv (see R3 derivation):
// w[h][ui][di],  m = 8*(ui-63) + 2*(di-3) - 1 + 2*h  (always odd),
// w = -2/(pi*m)^2.  Staged into LDS at kernel start (thread-indexed access).
// ---------------------------------------------------------------------------
struct alignas(16) WTab { float w[2 * 127 * 8]; };
constexpr WTab make_wtab() {
    WTab t{};
    for (int h = 0; h < 2; ++h)
        for (int ui = 0; ui < 127; ++ui)
            for (int di = 0; di < 8; ++di) {
                int m = 8 * (ui - 63) + 2 * (di - 3) - 1 + 2 * h;
                double md = (double)m;
                t.w[(h * 127 + ui) * 8 + di] =
                    (float)(-2.0 / (PI_D * PI_D * md * md));
            }
    return t;
}
__device__ constexpr WTab WTAB = make_wtab();

// ---------------------------------------------------------------------------
// Kernel 1: ramp filter, parity-deinterleaved blocked conv, weights in LDS.
// 128 threads: wave 0 -> even outputs (odd sources), wave 1 -> odd outputs.
// Per iteration: 1 data ds_read_b128 (lane-varying) + 2 weight ds_read_b128
// (wave-uniform -> broadcast) feeding 16 FMAs. Also zeroes a slice of d_out.
// ---------------------------------------------------------------------------
__global__ __launch_bounds__(128) void ramp_filter_kernel(
        const float* __restrict__ x, float* __restrict__ ft,
        float* __restrict__ out, int n4, int pb4) {
    const int bx = blockIdx.x;
    const int b  = blockIdx.y;
    const int t  = threadIdx.x;   // 0..127

    // XCD-locality swizzle: consecutive-%8 blocks get runs of consecutive a
    // (180 = 8 runs of 22/23), so the strided x cachelines are shared within
    // one XCD's L2. Pure locality heuristic — any mapping is correct.
    const int rr = bx & 7, qq = bx >> 3;
    const int a  = 22 * rr + min(rr, 4) + qq;

    // --- fold in zeroing of d_out (atomicAdd target) ---
    {
        float4* oz = (float4*)out;
        const float4 z4 = make_float4(0.f, 0.f, 0.f, 0.f);
        const int base4 = (b * NA + bx) * pb4;
        for (int i = t; i < pb4; i += 128) {
            int idx = base4 + i;
            if (idx < n4) oz[idx] = z4;
        }
    }

    __shared__ float Ef[768];        // even samples, 256 zero floats each side
    __shared__ float Of[768];        // odd samples
    __shared__ float W[2 * 127 * 8]; // weight table (8128 B)

    // stage weights: coalesced float4 from .rodata
    {
        const float4* wsrc = (const float4*)WTAB.w;   // 508 float4
        float4* wdst = (float4*)W;
        #pragma unroll
        for (int k = 0; k < 4; ++k) {
            int i = t + k * 128;
            if (i < 508) wdst[i] = wsrc[i];
        }
    }

    const float2 z2 = make_float2(0.f, 0.f);
    *(float2*)&Ef[2 * t]       = z2;
    *(float2*)&Ef[512 + 2 * t] = z2;
    *(float2*)&Of[2 * t]       = z2;
    *(float2*)&Of[512 + 2 * t] = z2;

    // x is (B,1,DET,NA): column (b,:,a); deinterleave by parity
    const float* xc = x + (size_t)(b * DET) * NA + a;
    float v0 = xc[(4 * t + 0) * NA];
    float v1 = xc[(4 * t + 1) * NA];
    float v2 = xc[(4 * t + 2) * NA];
    float v3 = xc[(4 * t + 3) * NA];
    *(float2*)&Ef[256 + 2 * t] = make_float2(v0, v2);
    *(float2*)&Of[256 + 2 * t] = make_float2(v1, v3);
    __syncthreads();

    const int half = t >> 6;
    const int tp   = t & 63;
    const float4* src4  = (const float4*)(half ? Ef : Of);  // opposite parity
    const float4* self4 = (const float4*)(half ? Of : Ef);
    const float*  Wh    = W + half * (127 * 8);

    float acc0 = 0.f, acc1 = 0.f, acc2 = 0.f, acc3 = 0.f;
    #pragma unroll 2
    for (int ui = 0; ui < 127; ++ui) {
        const float4 w0 = *(const float4*)&Wh[ui * 8];      // w[0..3]
        const float4 w1 = *(const float4*)&Wh[ui * 8 + 4];  // w[4..7]
        float4 s4 = src4[tp + (127 - ui)];
        acc0 = fmaf(s4.x, w0.w, fmaf(s4.y, w0.z, fmaf(s4.z, w0.y, fmaf(s4.w, w0.x, acc0))));
        acc1 = fmaf(s4.x, w1.x, fmaf(s4.y, w0.w, fmaf(s4.z, w0.z, fmaf(s4.w, w0.y, acc1))));
        acc2 = fmaf(s4.x, w1.y, fmaf(s4.y, w1.x, fmaf(s4.z, w0.w, fmaf(s4.w, w0.z, acc2))));
        acc3 = fmaf(s4.x, w1.z, fmaf(s4.y, w1.y, fmaf(s4.z, w1.x, fmaf(s4.w, w0.w, acc3))));
    }

    float4 sf = self4[64 + tp];
    acc0 = fmaf(0.5f, sf.x, acc0);
    acc1 = fmaf(0.5f, sf.y, acc1);
    acc2 = fmaf(0.5f, sf.z, acc2);
    acc3 = fmaf(0.5f, sf.w, acc3);

    // outputs d = 8*tp + 2*j + half
    float* o = ft + (b * NA + a) * DET + 8 * tp + half;
    o[0] = acc0;
    o[2] = acc1;
    o[4] = acc2;
    o[6] = acc3;
}

// ---------------------------------------------------------------------------
// Kernel 2: backprojection with paired LDS lines — one aligned ds_read_b64
// per interp: pline[i] = (L[i], L[i+1]), sentinel (L[511], 0) from staging.
// ---------------------------------------------------------------------------
__device__ __forceinline__ float interp1(const float2* __restrict__ L, float pos) {
    float pf = floorf(pos);
    float fr = pos - pf;
    float2 g = L[(int)pf];
    float v  = fmaf(fr, g.y - g.x, g.x);
    return pos <= (float)(DET - 1) ? v : 0.0f;
}

__global__ __launch_bounds__(256) void backproject_kernel(
        const float* __restrict__ ft, float* __restrict__ out) {
    const int bz = blockIdx.z;
    const int b  = bz / NSPLIT;
    const int sp = bz - b * NSPLIT;
    const int r0 = blockIdx.y * 32;
    const int c0 = blockIdx.x * 32;
    const int tid = threadIdx.x;
    const int tx = tid & 15;
    const int ty = tid >> 4;

    __shared__ float2 pline[CHUNK][PSTRIDE];   // 20560 B -> 7 blocks/CU

    // guard pixels (r/c >= OUT) clamp their coordinate so pos stays in
    // [0.03, 511.97]; their stores are guarded off below.
    const float xpr = (float)(min(r0 + ty, OUT - 1) - RAD);
    const float ypr = (float)(min(c0 + tx, OUT - 1) - RAD);

    float a00 = 0.0f, a01 = 0.0f, a10 = 0.0f, a11 = 0.0f;

    const float* base = ft + (b * NA + sp * APB) * DET;

    for (int rd = 0; rd < APB / CHUNK; ++rd) {
        __syncthreads();
        const float* gsrc = base + rd * CHUNK * DET;
        #pragma unroll
        for (int k = 0; k < 3; ++k) {
            int j4 = tid + k * 256;                    // 640 float4 per chunk
            if (j4 < CHUNK * DET / 4) {
                const float4 v = *(const float4*)&gsrc[j4 * 4];
                int c = j4 >> 7;                       // line within chunk
                int d = (j4 & 127) << 2;               // detector offset
                float v4 = (d + 4 < DET) ? gsrc[j4 * 4 + 4] : 0.0f;
                float2* dst = &pline[c][d];
                *(float4*)&dst[0] = make_float4(v.x, v.y, v.y, v.z);
                *(float4*)&dst[2] = make_float4(v.z, v.w, v.w, v4);
            }
        }
        __syncthreads();

        const int abase = sp * APB + rd * CHUNK;
        #pragma unroll
        for (int i = 0; i < CHUNK; ++i) {
            const float cv = TRIG.c[abase + i];
            const float sv = TRIG.s[abase + i];
            // pos = ypr*cos - xpr*sin + det/2
            float p00 = fmaf(ypr, cv, fmaf(xpr, -sv, 256.0f));
            float p01 = fmaf(16.0f, cv, p00);       // col+16
            float p10 = fmaf(-16.0f, sv, p00);      // row+16
            float p11 = fmaf(-16.0f, sv, p01);      // row+16, col+16
            const float2* L = pline[i];
            a00 += interp1(L, p00);
            a01 += interp1(L, p01);
            a10 += interp1(L, p10);
            a11 += interp1(L, p11);
        }
    }

    const float scale = (float)(PI_D / (2.0 * NA));
    const int r = r0 + ty;
    const int c = c0 + tx;
    float* ob = out + b * OUT * OUT;
    if (r < OUT) {
        if (c < OUT)      atomicAdd(&ob[r * OUT + c],      a00 * scale);
        if (c + 16 < OUT) atomicAdd(&ob[r * OUT + c + 16], a01 * scale);
    }
    if (r + 16 < OUT) {
        if (c < OUT)      atomicAdd(&ob[(r + 16) * OUT + c],      a10 * scale);
        if (c + 16 < OUT) atomicAdd(&ob[(r + 16) * OUT + c + 16], a11 * scale);
    }
}

extern "C" void kernel_launch(void* const* d_in, const int* in_sizes, int n_in,
                              void* d_out, int out_size, void* d_ws, size_t ws_size,
                              hipStream_t stream) {
    const float* x = (const float*)d_in[0];
    float* ft  = (float*)d_ws;     // B*NA*DET*4 = 1.47 MB scratch
    float* out = (float*)d_out;

    const int B = in_sizes[0] / (DET * NA);   // 4

    const int n4  = out_size / 4;                       // float4 count
    const int pb4 = (n4 + NA * B - 1) / (NA * B);       // float4s zeroed/block

    ramp_filter_kernel<<<dim3(NA, B), 128, 0, stream>>>(x, ft, out, n4, pb4);
    backproject_kernel<<<dim3((OUT + 31) / 32, (OUT + 31) / 32, B * NSPLIT),
                         256, 0, stream>>>(ft, out);
}

// Round 6
// 109.818 us; speedup vs baseline: 1.0999x; 1.0999x over previous
//
#include <hip/hip_runtime.h>
#include <math.h>

#define DET 512
#define NA  180
#define OUT 362   // floor(sqrt(512^2/2))
#define RAD 181   // OUT/2

#define NSPLIT 3        // angle partitions per (b, tile)
#define APB    60       // angles per block (NA / NSPLIT)
#define CHUNK  10       // angle lines staged per barrier
#define LSTRIDE 516     // line stride in floats

constexpr double PI_D = 3.14159265358979323846;

// ---------------------------------------------------------------------------
// Compile-time trig table. Index ONLY with block/loop-uniform values.
// ---------------------------------------------------------------------------
constexpr double tsin(double x) {
    double x2 = x * x;
    return x * (1.0 + x2 * (-1.0/6 + x2 * (1.0/120 + x2 * (-1.0/5040 +
               x2 * (1.0/362880 + x2 * (-1.0/39916800))))));
}
constexpr double tcos(double x) {
    double x2 = x * x;
    return 1.0 + x2 * (-0.5 + x2 * (1.0/24 + x2 * (-1.0/720 +
               x2 * (1.0/40320 + x2 * (-1.0/3628800)))));
}

struct alignas(16) Trig { float c[NA]; float s[NA]; };
constexpr Trig make_trig() {
    Trig t{};
    constexpr double r = PI_D / 180.0;
    for (int k = 0; k < NA; ++k) {
        double c, s;
        if (k <= 45)       { c =  tcos(k * r);          s =  tsin(k * r); }
        else if (k <= 90)  { c =  tsin((90 - k) * r);   s =  tcos((90 - k) * r); }
        else if (k <= 135) { c = -tsin((k - 90) * r);   s =  tcos((k - 90) * r); }
        else               { c = -tcos((180 - k) * r);  s =  tsin((180 - k) * r); }
        t.c[k] = (float)c; t.s[k] = (float)s;
    }
    return t;
}
__device__ constexpr Trig TRIG = make_trig();

// ---------------------------------------------------------------------------
// Ramp-filter weight table, parity-blocked conv:
// w[h][ui][di], m = 8*(ui-63) + 2*(di-3) - 1 + 2*h (always odd), w = -2/(pi*m)^2
// ---------------------------------------------------------------------------
struct alignas(16) WTab { float w[2 * 127 * 8]; };
constexpr WTab make_wtab() {
    WTab t{};
    for (int h = 0; h < 2; ++h)
        for (int ui = 0; ui < 127; ++ui)
            for (int di = 0; di < 8; ++di) {
                int m = 8 * (ui - 63) + 2 * (di - 3) - 1 + 2 * h;
                double md = (double)m;
                t.w[(h * 127 + ui) * 8 + di] =
                    (float)(-2.0 / (PI_D * PI_D * md * md));
            }
    return t;
}
__device__ constexpr WTab WTAB = make_wtab();

// ---------------------------------------------------------------------------
// Kernel 1: ramp filter. Wave 0 -> even outputs (odd sources), wave 1 -> odd.
// Weight address made provably wave-uniform via readfirstlane -> s_load
// (SMEM pipe); per iteration 1 lane-varying ds_read_b128 feeds 16 FMAs.
// Also zeroes a slice of d_out (atomicAdd target for kernel 2).
// ---------------------------------------------------------------------------
__global__ __launch_bounds__(128) void ramp_filter_kernel(
        const float* __restrict__ x, float* __restrict__ ft,
        float* __restrict__ out, int n4, int pb4) {
    const int bx = blockIdx.x;
    const int b  = blockIdx.y;
    const int t  = threadIdx.x;   // 0..127

    // XCD-locality swizzle: blocks with equal bx%8 get consecutive angles.
    const int rr = bx & 7, qq = bx >> 3;
    const int a  = 22 * rr + min(rr, 4) + qq;

    // --- fold in zeroing of d_out ---
    {
        float4* oz = (float4*)out;
        const float4 z4 = make_float4(0.f, 0.f, 0.f, 0.f);
        const int base4 = (b * NA + bx) * pb4;
        for (int i = t; i < pb4; i += 128) {
            int idx = base4 + i;
            if (idx < n4) oz[idx] = z4;
        }
    }

    __shared__ float Ef[768];   // even samples, 256 zero floats each side
    __shared__ float Of[768];   // odd samples

    const float2 z2 = make_float2(0.f, 0.f);
    *(float2*)&Ef[2 * t]       = z2;
    *(float2*)&Ef[512 + 2 * t] = z2;
    *(float2*)&Of[2 * t]       = z2;
    *(float2*)&Of[512 + 2 * t] = z2;

    // x is (B,1,DET,NA): column (b,:,a); deinterleave by parity
    const float* xc = x + (size_t)(b * DET) * NA + a;
    float v0 = xc[(4 * t + 0) * NA];
    float v1 = xc[(4 * t + 1) * NA];
    float v2 = xc[(4 * t + 2) * NA];
    float v3 = xc[(4 * t + 3) * NA];
    *(float2*)&Ef[256 + 2 * t] = make_float2(v0, v2);
    *(float2*)&Of[256 + 2 * t] = make_float2(v1, v3);
    __syncthreads();

    // half is wave-uniform; make it provably so -> weight reads become s_load
    const int half = __builtin_amdgcn_readfirstlane(t >> 6);
    const int tp   = t & 63;
    const float4* src4  = (const float4*)(half ? Ef : Of);  // opposite parity
    const float4* self4 = (const float4*)(half ? Of : Ef);
    const float* __restrict__ Wh = WTAB.w + half * (127 * 8);

    float acc0 = 0.f, acc1 = 0.f, acc2 = 0.f, acc3 = 0.f;
    #pragma unroll 2
    for (int ui = 0; ui < 127; ++ui) {
        const float4 w0 = *(const float4*)&Wh[ui * 8];      // s_load_dwordx4
        const float4 w1 = *(const float4*)&Wh[ui * 8 + 4];
        float4 s4 = src4[tp + (127 - ui)];
        acc0 = fmaf(s4.x, w0.w, fmaf(s4.y, w0.z, fmaf(s4.z, w0.y, fmaf(s4.w, w0.x, acc0))));
        acc1 = fmaf(s4.x, w1.x, fmaf(s4.y, w0.w, fmaf(s4.z, w0.z, fmaf(s4.w, w0.y, acc1))));
        acc2 = fmaf(s4.x, w1.y, fmaf(s4.y, w1.x, fmaf(s4.z, w0.w, fmaf(s4.w, w0.z, acc2))));
        acc3 = fmaf(s4.x, w1.z, fmaf(s4.y, w1.y, fmaf(s4.z, w1.x, fmaf(s4.w, w0.w, acc3))));
    }

    float4 sf = self4[64 + tp];
    acc0 = fmaf(0.5f, sf.x, acc0);
    acc1 = fmaf(0.5f, sf.y, acc1);
    acc2 = fmaf(0.5f, sf.z, acc2);
    acc3 = fmaf(0.5f, sf.w, acc3);

    float* o = ft + (b * NA + a) * DET + 8 * tp + half;
    o[0] = acc0;
    o[2] = acc1;
    o[4] = acc2;
    o[6] = acc3;
}

// ---------------------------------------------------------------------------
// Kernel 2: backprojection. 4-byte LDS line (zero bank conflicts: per-wave
// index spread <= ~16 < 32). Maskless interp for blocks whose max pixel
// radius <= 255 (pos provably in (0, 511]); masked only for corner blocks.
// ---------------------------------------------------------------------------
__device__ __forceinline__ float interp_fast(const float* __restrict__ L, float pos) {
    float fr = __builtin_amdgcn_fractf(pos);
    int   i0 = (int)pos;                 // trunc == floor (pos > 0)
    float g0 = L[i0];
    float g1 = L[i0 + 1];                // [512] zero sentinel
    return fmaf(fr, g1 - g0, g0);
}
__device__ __forceinline__ float interp_masked(const float* __restrict__ L, float pos) {
    float v = interp_fast(L, pos);
    return pos <= (float)(DET - 1) ? v : 0.0f;
}

__global__ __launch_bounds__(256) void backproject_kernel(
        const float* __restrict__ ft, float* __restrict__ out) {
    const int bz = blockIdx.z;
    const int b  = bz / NSPLIT;
    const int sp = bz - b * NSPLIT;
    const int r0 = blockIdx.y * 32;
    const int c0 = blockIdx.x * 32;
    const int tid = threadIdx.x;
    const int tx = tid & 15;
    const int ty = tid >> 4;

    __shared__ float line[CHUNK][LSTRIDE];   // 20.6 KB -> 7 blocks/CU

    if (tid < CHUNK) line[tid][512] = 0.0f;  // zero sentinels (written once)

    // guard pixels clamp coords (stores guarded off); pos stays valid
    const float xpr = (float)(min(r0 + ty, OUT - 1) - RAD);
    const float ypr = (float)(min(c0 + tx, OUT - 1) - RAD);

    float a00 = 0.0f, a01 = 0.0f, a10 = 0.0f, a11 = 0.0f;

    const float* base = ft + (b * NA + sp * APB) * DET;

    auto run = [&](auto&& interp) {
        for (int rd = 0; rd < APB / CHUNK; ++rd) {
            __syncthreads();
            const float* gsrc = base + rd * CHUNK * DET;
            // CHUNK*DET/4 = 1280 float4 = 5 * 256 exactly
            #pragma unroll
            for (int k = 0; k < 5; ++k) {
                int j4 = tid + k * 256;
                float4 v = *(const float4*)&gsrc[j4 * 4];
                int ci = j4 >> 7;                  // line within chunk [0,10)
                int d  = (j4 & 127) << 2;          // detector offset [0,512)
                *(float4*)&line[ci][d] = v;
            }
            __syncthreads();

            const int abase = sp * APB + rd * CHUNK;
            #pragma unroll
            for (int i = 0; i < CHUNK; ++i) {
                const float cv = TRIG.c[abase + i];
                const float sv = TRIG.s[abase + i];
                // pos = ypr*cos - xpr*sin + det/2
                float p00 = fmaf(ypr, cv, fmaf(xpr, -sv, 256.0f));
                float p01 = fmaf(16.0f, cv, p00);       // col+16
                float p10 = fmaf(-16.0f, sv, p00);      // row+16
                float p11 = fmaf(-16.0f, sv, p01);      // row+16, col+16
                const float* L = line[i];
                a00 += interp(L, p00);
                a01 += interp(L, p01);
                a10 += interp(L, p10);
                a11 += interp(L, p11);
            }
        }
    };

    // Block-uniform mask elision: max pixel radius in this block (clamped
    // coords). Integer pixels with |off|<=181 can't land in (254.56, 255],
    // so radius^2 <= 255^2 guarantees true pos in [1, 511] -> mask dead.
    {
        float drm = fmaxf(fabsf((float)(r0 - RAD)),
                          fabsf((float)(min(r0 + 31, OUT - 1) - RAD)));
        float dcm = fmaxf(fabsf((float)(c0 - RAD)),
                          fabsf((float)(min(c0 + 31, OUT - 1) - RAD)));
        if (drm * drm + dcm * dcm <= 65025.0f)   // 255^2
            run([](const float* __restrict__ L, float p) { return interp_fast(L, p); });
        else
            run([](const float* __restrict__ L, float p) { return interp_masked(L, p); });
    }

    const float scale = (float)(PI_D / (2.0 * NA));
    const int r = r0 + ty;
    const int c = c0 + tx;
    float* ob = out + b * OUT * OUT;
    if (r < OUT) {
        if (c < OUT)      atomicAdd(&ob[r * OUT + c],      a00 * scale);
        if (c + 16 < OUT) atomicAdd(&ob[r * OUT + c + 16], a01 * scale);
    }
    if (r + 16 < OUT) {
        if (c < OUT)      atomicAdd(&ob[(r + 16) * OUT + c],      a10 * scale);
        if (c + 16 < OUT) atomicAdd(&ob[(r + 16) * OUT + c + 16], a11 * scale);
    }
}

extern "C" void kernel_launch(void* const* d_in, const int* in_sizes, int n_in,
                              void* d_out, int out_size, void* d_ws, size_t ws_size,
                              hipStream_t stream) {
    const float* x = (const float*)d_in[0];
    float* ft  = (float*)d_ws;     // B*NA*DET*4 = 1.47 MB scratch
    float* out = (float*)d_out;

    const int B = in_sizes[0] / (DET * NA);   // 4

    const int n4  = out_size / 4;                       // float4 count
    const int pb4 = (n4 + NA * B - 1) / (NA * B);       // float4s zeroed/block

    ramp_filter_kernel<<<dim3(NA, B), 128, 0, stream>>>(x, ft, out, n4, pb4);
    backproject_kernel<<<dim3((OUT + 31) / 32, (OUT + 31) / 32, B * NSPLIT),
                         256, 0, stream>>>(ft, out);
}